// Round 7
// baseline (266.015 us; speedup 1.0000x reference)
//
#include <hip/hip_runtime.h>

typedef unsigned short u16;
typedef float  f32x4  __attribute__((ext_vector_type(4)));
typedef __bf16 bf16x8 __attribute__((ext_vector_type(8)));
typedef u16    u16x4  __attribute__((ext_vector_type(4)));
typedef u16    u16x8  __attribute__((ext_vector_type(8)));

#define D_MODEL 1024
#define D_INNER 2048
#define B_SZ    2
#define SEQ     4096
#define MROWS   (B_SZ * SEQ)       // 8192
#define LTAPS   64                 // f[tau] ~ 0.4^tau -> negligible at 64
#define KFIR    192                // FIR K-window per 128-t tile
#define CVROW   200                // VT row stride (u16): 400 B, 16B-aligned

__device__ __forceinline__ u16 f2bf(float f) {
    return __builtin_bit_cast(u16, (__bf16)f);   // HW v_cvt (RTNE) on gfx950
}
__device__ __forceinline__ float bf2f(u16 h) {
    unsigned u = ((unsigned)h) << 16;
    return __builtin_bit_cast(float, u);
}

typedef __attribute__((address_space(1))) void gv_t;
typedef __attribute__((address_space(3))) void lv_t;
__device__ __forceinline__ void glds16(const u16* g, u16* l) {
    __builtin_amdgcn_global_load_lds((gv_t*)g, (lv_t*)l, 16, 0, 0);
}
// gfx9 waitcnt imm: vm[3:0]+[15:14], exp[6:4], lgkm[11:8]
#define WAIT_VM0   0x0F70   // vmcnt(0)
#define WAIT_LGKM0 0xC07F   // lgkmcnt(0)
#define SCHED_FENCE() asm volatile("" ::: "memory")

// ---------------------------------------------------------------------------
// Prep (one launch): blocks [0,8192) cvt x->bf16; [8192,10240) transpose Win;
// [10240,12288) transpose Wout; block 12288 builds Amat192[128][192] bf16:
// Amat192[m][j] = f[64+m-j] (0 outside [0,64)), f[tau] = Cp^T tanh(A)^tau Bp
// (+Dp at tau=0).
// ---------------------------------------------------------------------------
__device__ __forceinline__ void transpose_tile(
    const float* __restrict__ in, u16* __restrict__ out,
    int R, int C, int c0, int r0, int tid, float (*tile)[33])
{
    const int tx = tid & 31, ty = tid >> 5;   // 32 x 8
    for (int k = 0; k < 32; k += 8)
        tile[ty + k][tx] = in[(size_t)(r0 + ty + k) * C + c0 + tx];
    __syncthreads();
    for (int k = 0; k < 32; k += 8)
        out[(size_t)(c0 + ty + k) * R + r0 + tx] = f2bf(tile[tx][ty + k]);
}

__global__ __launch_bounds__(256) void prep_kernel(
    const float* __restrict__ x, u16* __restrict__ xb,
    const float* __restrict__ Win, u16* __restrict__ WinT,
    const float* __restrict__ Wout, u16* __restrict__ WoutT,
    const float* __restrict__ A, const float* __restrict__ Bp,
    const float* __restrict__ Cp, const float* __restrict__ Dp,
    u16* __restrict__ Amat192)
{
    __shared__ float tile[32][33];
    __shared__ float fs[LTAPS];
    const int bx = blockIdx.x, tid = threadIdx.x;
    if (bx < 8192) {
        size_t i = ((size_t)bx * 256 + tid) * 4;
        f32x4 v = *(const f32x4*)(x + i);
        u16x4 o;
        o.x = f2bf(v.x); o.y = f2bf(v.y); o.z = f2bf(v.z); o.w = f2bf(v.w);
        *(u16x4*)(xb + i) = o;
    } else if (bx < 10240) {
        const int flat = bx - 8192;                      // Win: 1024 x 2048
        transpose_tile(Win, WinT, 1024, 2048,
                       (flat & 63) * 32, (flat >> 6) * 32, tid, tile);
    } else if (bx < 12288) {
        const int flat = bx - 10240;                     // Wout: 2048 x 1024
        transpose_tile(Wout, WoutT, 2048, 1024,
                       (flat & 31) * 32, (flat >> 5) * 32, tid, tile);
    } else {
        if (tid < 64) {
            const int i = tid & 15;          // lanes replicate in groups of 16
            float Atr[16];
            for (int j = 0; j < 16; j++) Atr[j] = tanhf(A[i * 16 + j]);
            float p = Bp[i];
            const float c  = Cp[i];
            const float d0 = Dp[0];
            for (int t = 0; t < LTAPS; t++) {
                float fv = c * p;
                fv += __shfl_xor(fv, 1); fv += __shfl_xor(fv, 2);
                fv += __shfl_xor(fv, 4); fv += __shfl_xor(fv, 8);
                if (tid == 0) fs[t] = fv + (t == 0 ? d0 : 0.f);
                float n0 = 0.f, n1 = 0.f, n2 = 0.f, n3 = 0.f;
                #pragma unroll
                for (int j = 0; j < 4; j++) {
                    n0 = fmaf(Atr[j],      __shfl(p, j),      n0);
                    n1 = fmaf(Atr[j + 4],  __shfl(p, j + 4),  n1);
                    n2 = fmaf(Atr[j + 8],  __shfl(p, j + 8),  n2);
                    n3 = fmaf(Atr[j + 12], __shfl(p, j + 12), n3);
                }
                p = (n0 + n1) + (n2 + n3);
            }
        }
        __syncthreads();
        for (int idx = tid; idx < 128 * KFIR; idx += 256) {
            const int i = idx / KFIR, j = idx % KFIR;
            const int tau = 64 + i - j;
            float v = (tau >= 0 && tau < LTAPS) ? fs[tau] : 0.f;
            Amat192[idx] = f2bf(v);
        }
    }
}

// ---------------------------------------------------------------------------
// bt-GEMM: C[m][n] = sum_k A[m][k]*BT[n][k] + bias
// BM=BN=128, BK=64, 256 thr, 16x16x32 bf16 MFMA (swapped operands: thread's
// f32x4 = 4 consecutive n-cols at row m -> vectorized stores).
// K-loop (R5 structure, BK doubled): single LDS buffer; per iter:
//   wait vm0; barrier (tile landed); ds_read all 16 frags; lgkm0;
//   barrier (LDS free); stage NEXT tile (8x glds16); 32 MFMAs.
// XCD-aware tile remap. MODE 0: bf16 out; MODE 1: fp32 out.
// BIAS_M: bias indexed by m-row (per-channel) instead of n-col.
// ---------------------------------------------------------------------------
template <int MODE, bool BIAS_M>
__global__ __launch_bounds__(256) void gemm_bt_kernel(
    const u16* __restrict__ A, const u16* __restrict__ BT,
    void* __restrict__ Cout, const float* __restrict__ bias,
    int M, int N, int K)
{
    __shared__ u16 As[128 * 64];
    __shared__ u16 Bs[128 * 64];
    const int tid = threadIdx.x, lane = tid & 63, wid = tid >> 6;
    const int nTiles = gridDim.x;
    const int bid = blockIdx.x + nTiles * blockIdx.y;
    const int xcd = bid & 7;
    const int loc = bid >> 3;
    const int strip = gridDim.y >> 3;                 // m-tiles per XCD strip
    const int mt  = xcd * strip + (loc & (strip - 1));
    const int nt  = loc / strip;
    const int m0 = mt * 128, n0 = nt * 128;
    // staging: lane -> row lane>>3 (+{0,8,16,24} per wave), col (lane&7)*8
    const int sr = wid * 32 + (lane >> 3);
    const int sc = (lane & 7) * 8;
    const u16* ga = A  + (size_t)(m0 + sr) * K + sc;
    const u16* gb = BT + (size_t)(n0 + sr) * K + sc;
    u16* la = As + wid * 2048;
    u16* lb = Bs + wid * 2048;
    const int wm = (wid & 1) * 64, wn = (wid >> 1) * 64;
    const int fr = lane & 15, fq = lane >> 4;
    f32x4 acc[4][4] = {};
    // prologue: stage tile 0 (8 glds16; each wave covers its 32 rows)
    #pragma unroll
    for (int r = 0; r < 32; r += 8) {
        glds16(ga + (size_t)r * K, la + r * 64);
        glds16(gb + (size_t)r * K, lb + r * 64);
    }
    const int iters = K >> 6;
    for (int it = 0; it < iters; ++it) {
        __builtin_amdgcn_s_waitcnt(WAIT_VM0);     // staged tile landed in LDS
        __builtin_amdgcn_s_barrier();
        SCHED_FENCE();
        bf16x8 af[4][2], bfr[4][2];
        #pragma unroll
        for (int i = 0; i < 4; i++)
            #pragma unroll
            for (int kk = 0; kk < 2; kk++) {
                af[i][kk]  = *(const bf16x8*)(As + (wm + i * 16 + fr) * 64 + kk * 32 + fq * 8);
                bfr[i][kk] = *(const bf16x8*)(Bs + (wn + i * 16 + fr) * 64 + kk * 32 + fq * 8);
            }
        SCHED_FENCE();
        __builtin_amdgcn_s_waitcnt(WAIT_LGKM0);   // fragments in registers
        __builtin_amdgcn_s_barrier();             // LDS free for overwrite
        SCHED_FENCE();
        if (it + 1 < iters) {                     // stage next tile; latency
            const int k0 = (it + 1) << 6;         // hides under the MFMAs
            #pragma unroll
            for (int r = 0; r < 32; r += 8) {
                glds16(ga + k0 + (size_t)r * K, la + r * 64);
                glds16(gb + k0 + (size_t)r * K, lb + r * 64);
            }
        }
        #pragma unroll
        for (int kk = 0; kk < 2; kk++)
            #pragma unroll
            for (int mi = 0; mi < 4; mi++)
                #pragma unroll
                for (int ni = 0; ni < 4; ni++)
                    acc[mi][ni] = __builtin_amdgcn_mfma_f32_16x16x32_bf16(
                        bfr[ni][kk], af[mi][kk], acc[mi][ni], 0, 0, 0);
    }
    // epilogue: thread owns row m = ..+fr, cols n = ..+fq*4+{0..3}
    for (int mi = 0; mi < 4; mi++) {
        const int row = m0 + wm + mi * 16 + fr;
        const float bm = BIAS_M ? bias[row] : 0.f;
        for (int ni = 0; ni < 4; ni++) {
            const int colb = n0 + wn + ni * 16 + fq * 4;
            f32x4 v = acc[mi][ni];
            if constexpr (BIAS_M) {
                v.x += bm; v.y += bm; v.z += bm; v.w += bm;
            } else {
                const f32x4 bv = *(const f32x4*)(bias + colb);
                v.x += bv.x; v.y += bv.y; v.z += bv.z; v.w += bv.w;
            }
            if constexpr (MODE == 0) {
                u16x4 o;
                o.x = f2bf(v.x); o.y = f2bf(v.y); o.z = f2bf(v.z); o.w = f2bf(v.w);
                *(u16x4*)((u16*)Cout + (size_t)row * N + colb) = o;
            } else {
                *(f32x4*)((float*)Cout + (size_t)row * N + colb) = v;
            }
        }
    }
}

// ---------------------------------------------------------------------------
// Fused depthwise-conv(4) + 64-tap FIR (MFMA Toeplitz) + silu.
// Input uT[c][t] (c-major, t contiguous) -> conv loads are u16x8 along t.
// Block: 128 t x 128 c, one batch. Conv fills VT[c][j], j = s-(t0-64),
// s-window [t0-64, t0+128) = 192 cols, row stride CVROW=200.
// FIR: y[t0+m][c0+n] = sum_j Amat192[m][j] * VT[n][j]; A-frags from global
// (L2-hot 48 KB shared by all blocks). Thread's f32x4 = 4 consecutive
// channels -> vectorized u16x4 Y stores. grid (16, 32, 2), 256 thr.
// ---------------------------------------------------------------------------
__global__ __launch_bounds__(256) void conv_fir_mfma_kernel(
    const u16* __restrict__ uT, const float* __restrict__ cw,
    const float* __restrict__ cb, const u16* __restrict__ Amat192,
    u16* __restrict__ Y)
{
    __shared__ u16 VT[128 * CVROW];          // 51200 B
    const int tid = threadIdx.x;
    const int c0 = blockIdx.x * 128, t0 = blockIdx.y * 128, b = blockIdx.z;
    // ---- conv phase: thread = one channel row, 96 consecutive s ----
    {
        const int tx = tid & 127, ty = tid >> 7;
        const int c = c0 + tx;
        const f32x4 w = *(const f32x4*)(cw + c * 4);
        const float cbv = cb[c];
        const u16* urow = uT + (size_t)c * MROWS + (size_t)b * SEQ;
        const int j0 = ty * 96;
        const int s0 = t0 - 64 + j0;         // multiple of 32 (may be -64)
        u16* vdst = VT + tx * CVROW + j0;
        float xm3 = 0.f, xm2 = 0.f, xm1 = 0.f;
        if (s0 > 0) {
            xm3 = bf2f(urow[s0 - 3]);
            xm2 = bf2f(urow[s0 - 2]);
            xm1 = bf2f(urow[s0 - 1]);
        }
        #pragma unroll
        for (int jj = 0; jj < 96; jj += 8) {
            const int s = s0 + jj;           // 8-chunk fully <0 or fully >=0
            u16x8 o;
            if (s < 0) {
                #pragma unroll
                for (int q = 0; q < 8; q++) o[q] = 0;
            } else {
                u16x8 r = *(const u16x8*)(urow + s);
                float xv[8];
                #pragma unroll
                for (int q = 0; q < 8; q++) xv[q] = bf2f(r[q]);
                o[0] = f2bf(cbv + w.x * xm3   + w.y * xm2   + w.z * xm1   + w.w * xv[0]);
                o[1] = f2bf(cbv + w.x * xm2   + w.y * xm1   + w.z * xv[0] + w.w * xv[1]);
                o[2] = f2bf(cbv + w.x * xm1   + w.y * xv[0] + w.z * xv[1] + w.w * xv[2]);
                #pragma unroll
                for (int q = 3; q < 8; q++)
                    o[q] = f2bf(cbv + w.x * xv[q-3] + w.y * xv[q-2] + w.z * xv[q-1] + w.w * xv[q]);
                xm3 = xv[5]; xm2 = xv[6]; xm1 = xv[7];
            }
            *(u16x8*)(vdst + jj) = o;
        }
    }
    __syncthreads();
    // ---- FIR phase: 4 waves, each 64t x 64c quadrant ----
    const int lane = tid & 63, wid = tid >> 6;
    const int wm = (wid & 1) * 64, wn = (wid >> 1) * 64;
    const int fr = lane & 15, fq = lane >> 4;
    f32x4 acc[4][4] = {};
    #pragma unroll
    for (int kq = 0; kq < 6; kq++) {
        const int k0 = kq * 32;
        bf16x8 af[4], bfr[4];
        #pragma unroll
        for (int mi = 0; mi < 4; mi++)
            af[mi] = *(const bf16x8*)(Amat192 + (wm + mi * 16 + fr) * KFIR + k0 + fq * 8);
        #pragma unroll
        for (int ni = 0; ni < 4; ni++)
            bfr[ni] = *(const bf16x8*)(VT + (wn + ni * 16 + fr) * CVROW + k0 + fq * 8);
        #pragma unroll
        for (int mi = 0; mi < 4; mi++)
            #pragma unroll
            for (int ni = 0; ni < 4; ni++)
                acc[mi][ni] = __builtin_amdgcn_mfma_f32_16x16x32_bf16(
                    bfr[ni], af[mi], acc[mi][ni], 0, 0, 0);
    }
    // epilogue: thread owns t = ..+fr, channels c = ..+fq*4+{0..3}
    #pragma unroll
    for (int ni = 0; ni < 4; ni++) {
        const int cbase = c0 + wn + ni * 16 + fq * 4;
        #pragma unroll
        for (int mi = 0; mi < 4; mi++) {
            const int trow = t0 + wm + mi * 16 + fr;
            f32x4 v = acc[mi][ni];
            u16x4 o;
            o.x = f2bf(v.x / (1.f + __expf(-v.x)));
            o.y = f2bf(v.y / (1.f + __expf(-v.y)));
            o.z = f2bf(v.z / (1.f + __expf(-v.z)));
            o.w = f2bf(v.w / (1.f + __expf(-v.w)));
            *(u16x4*)(Y + ((size_t)(b * SEQ + trow)) * D_INNER + cbase) = o;
        }
    }
}

// ---------------------------------------------------------------------------
extern "C" void kernel_launch(void* const* d_in, const int* in_sizes, int n_in,
                              void* d_out, int out_size, void* d_ws, size_t ws_size,
                              hipStream_t stream)
{
    const float* x    = (const float*)d_in[0];
    const float* Win  = (const float*)d_in[1];
    const float* bin  = (const float*)d_in[2];
    const float* cw   = (const float*)d_in[3];
    const float* cb   = (const float*)d_in[4];
    const float* A    = (const float*)d_in[5];
    const float* Bp   = (const float*)d_in[6];
    const float* Cp   = (const float*)d_in[7];
    const float* Dp   = (const float*)d_in[8];
    const float* Wout = (const float*)d_in[9];
    const float* bout = (const float*)d_in[10];
    float* out = (float*)d_out;

    char* ws = (char*)d_ws;
    u16* xb      = (u16*)(ws);                     // 8192x1024 bf16   16 MB
    u16* WinT    = (u16*)(ws + 16777216);          // 2048x1024 bf16    4 MB
    u16* WoutT   = (u16*)(ws + 20971520);          // 1024x2048 bf16    4 MB
    u16* uT      = (u16*)(ws + 25165824);          // 2048x8192 bf16   32 MB
    u16* Y       = (u16*)(ws + 58720256);          // 8192x2048 bf16   32 MB
    u16* Amat192 = (u16*)(ws + 92274688);          // 128x192 bf16     48 KB

    // all conversions/transposes/setup in one launch
    prep_kernel<<<12289, 256, 0, stream>>>(x, xb, Win, WinT, Wout, WoutT,
                                           A, Bp, Cp, Dp, Amat192);
    // uT[c][t] = (x @ W_in)^T + b_in  (M = channels, N = time)
    gemm_bt_kernel<0, true><<<dim3(64, 16), 256, 0, stream>>>(
        WinT, xb, uT, bin, D_INNER, MROWS, D_MODEL);
    // fused conv + SSM-as-FIR (MFMA Toeplitz) + silu -> Y[t][c]
    conv_fir_mfma_kernel<<<dim3(16, 32, 2), 256, 0, stream>>>(uT, cw, cb, Amat192, Y);
    // out = Y @ W_out + b_out  (fp32 out)
    gemm_bt_kernel<1, false><<<dim3(8, 64), 256, 0, stream>>>(
        Y, WoutT, out, bout, MROWS, D_MODEL, D_INNER);
}